// Round 3
// baseline (76.672 us; speedup 1.0000x reference)
//
#include <hip/hip_runtime.h>
#include <math.h>

#define NPTS   131072
#define BATCH  2
#define MBOX   128
#define NBOX   (BATCH * MBOX)       // 256
#define NFPS   512
#define THREADS 256

#define NSEG   64
#define SEGPTS 2048                 // points per segment
#define GRPBOX 16                   // boxes per phase-1 block group
#define NGRP   (NBOX / GRPBOX)      // 16
#define DWPB   (NPTS / 32)          // 4096 bitmask dwords per box

// ws layout (bytes): bits[NBOX*DWPB] (4 MiB) | prep[NBOX*8] f32 (8 KiB) | done[NGRP]
#define PREP_OFF (NBOX * DWPB * 4)
#define DONE_OFF (PREP_OFF + NBOX * 8 * 4)

// ---- prep: per-box params (fp32 ops bit-identical to passing kernel) + zero flags
__global__ __launch_bounds__(NBOX)
void roi_prep(const float* __restrict__ boxes,
              float* __restrict__ prep,
              int* __restrict__ done)
{
    const int tid = threadIdx.x;           // one thread per box
    if (tid < NGRP) done[tid] = 0;
    const float* bx = boxes + tid * 7;
    const float bdx = bx[3], bdy = bx[4], bdz = bx[5], h = bx[6];
    float* p = prep + tid * 8;
    p[0] = bx[0];
    p[1] = bx[1];
    p[2] = bx[2];
    p[3] = __fmul_rn(__fadd_rn(bdy, 2.0f), 0.5f);
    p[4] = __fmul_rn(__fadd_rn(bdx, 2.0f), 0.5f);
    p[5] = __fmul_rn(__fadd_rn(bdz, 2.0f), 0.5f);
    const float hp = -__fadd_rn(h, 1.5707963705062866f);  // fl32(pi/2)
    p[6] = (float)cos((double)hp);
    p[7] = (float)sin((double)hp);
}

// ---- fused: phase1 (ballot bitmask) + in-kernel phase2 (ordered compaction)
__global__ __launch_bounds__(THREADS, 4)
void roi_fused(const float* __restrict__ points,   // (N,4): [b,x,y,z]
               const float* __restrict__ prep,     // (NBOX,8)
               unsigned* __restrict__ bits,        // (NBOX, DWPB)
               int* __restrict__ done,             // (NGRP), pre-zeroed
               int* __restrict__ out_idx,          // (NBOX, 512)
               int* __restrict__ out_num)          // (NBOX)
{
    const int seg  = blockIdx.x;
    const int grp  = blockIdx.y;
    const int tid  = threadIdx.x;
    const int lane = tid & 63;
    const int w    = tid >> 6;

    __shared__ float s_box[GRPBOX][8];     // 512 B
    __shared__ int   s_wsum[THREADS / 64];

    if (tid < GRPBOX * 2) {                // 32 threads x 16B = 512 B
        const uint4* src = (const uint4*)(prep + grp * GRPBOX * 8);
        ((uint4*)&s_box[0][0])[tid] = src[tid];
    }
    __syncthreads();

    const int bB = grp >> 3;               // batch of this group's boxes (uniform)

    // load 8 points, strided by 64 within this wave's 512-point window
    const float4* p4 = (const float4*)points;
    const int wbase = seg * SEGPTS + w * 512;
    float px[8], py[8], pz[8];
    unsigned long long bok[8];
    #pragma unroll
    for (int j = 0; j < 8; ++j) {
        const float4 p = p4[wbase + j * 64 + lane];
        px[j] = p.y; py[j] = p.z; pz[j] = p.w;
        bok[j] = __ballot((int)p.x == bB);
    }

    unsigned* wdst = bits + (size_t)grp * GRPBOX * DWPB + seg * 64 + w * 16;
    #pragma unroll 1
    for (int bi = 0; bi < GRPBOX; ++bi) {
        const float cx = s_box[bi][0], cy = s_box[bi][1], cz = s_box[bi][2];
        const float hx = s_box[bi][3], hy = s_box[bi][4], hz = s_box[bi][5];
        const float c  = s_box[bi][6], s  = s_box[bi][7];
        unsigned long long bal[8];
        #pragma unroll
        for (int j = 0; j < 8; ++j) {
            const float ddx = __fsub_rn(px[j], cx);
            const float ddy = __fsub_rn(py[j], cy);
            const float ddz = __fsub_rn(pz[j], cz);
            const float lx  = __fadd_rn(__fmul_rn(ddx, c), __fmul_rn(ddy, s));
            const float ly  = __fadd_rn(__fmul_rn(-ddx, s), __fmul_rn(ddy, c));
            bal[j] = __ballot((fabsf(lx) <= hx) & (fabsf(ly) <= hy) &
                              (fabsf(ddz) <= hz)) & bok[j];
        }
        if (lane == 0) {
            uint4* dst = (uint4*)(wdst + bi * DWPB);
            dst[0] = make_uint4((unsigned)bal[0], (unsigned)(bal[0] >> 32),
                                (unsigned)bal[1], (unsigned)(bal[1] >> 32));
            dst[1] = make_uint4((unsigned)bal[2], (unsigned)(bal[2] >> 32),
                                (unsigned)bal[3], (unsigned)(bal[3] >> 32));
            dst[2] = make_uint4((unsigned)bal[4], (unsigned)(bal[4] >> 32),
                                (unsigned)bal[5], (unsigned)(bal[5] >> 32));
            dst[3] = make_uint4((unsigned)bal[6], (unsigned)(bal[6] >> 32),
                                (unsigned)bal[7], (unsigned)(bal[7] >> 32));
        }
    }

    // signal this segment-block done (stores drained by __syncthreads' vmcnt(0))
    __syncthreads();
    if (tid == 0)
        __hip_atomic_fetch_add(&done[grp], 1, __ATOMIC_RELEASE, __HIP_MEMORY_SCOPE_AGENT);

    if (seg >= GRPBOX) return;

    // ---- phase 2: this block compacts box grp*GRPBOX + seg ----
    const int box = grp * GRPBOX + seg;
    if (tid == 0) {
        while (__hip_atomic_load(&done[grp], __ATOMIC_ACQUIRE, __HIP_MEMORY_SCOPE_AGENT) < NSEG)
            __builtin_amdgcn_s_sleep(8);
    }
    __syncthreads();

    // thread t owns dwords [t*16, t*16+16) = points [t*512, (t+1)*512)
    unsigned v[16];
    const uint4* bp = (const uint4*)(bits + (size_t)box * DWPB + tid * 16);
    #pragma unroll
    for (int i = 0; i < 4; ++i) {
        const uint4 q = bp[i];
        v[4*i + 0] = q.x; v[4*i + 1] = q.y; v[4*i + 2] = q.z; v[4*i + 3] = q.w;
    }
    int cnt = 0;
    #pragma unroll
    for (int i = 0; i < 16; ++i) cnt += __popc(v[i]);

    int incl = cnt;
    #pragma unroll
    for (int off = 1; off < 64; off <<= 1) {
        const int x = __shfl_up(incl, off, 64);
        if (lane >= off) incl += x;
    }
    if (lane == 63) s_wsum[w] = incl;
    __syncthreads();

    int wpre = 0, total = 0;
    #pragma unroll
    for (int ww = 0; ww < THREADS / 64; ++ww) {
        const int x = s_wsum[ww];
        if (ww < w) wpre += x;
        total += x;
    }
    int pos = wpre + (incl - cnt);
    const int pn = total < NFPS ? total : NFPS;

    const int obase = box * NFPS;
    for (int k = tid; k < NFPS; k += THREADS)
        if (k >= pn) out_idx[obase + k] = 0;

    const int pt0 = tid * 512;
    #pragma unroll
    for (int i = 0; i < 16; ++i) {
        unsigned x = v[i];
        while (x) {
            const int b = __ffs(x) - 1;
            if (pos < NFPS) out_idx[obase + pos] = pt0 + i * 32 + b;
            ++pos;
            x &= x - 1;
        }
    }
    if (tid == 0) out_num[box] = pn;
}

extern "C" void kernel_launch(void* const* d_in, const int* in_sizes, int n_in,
                              void* d_out, int out_size, void* d_ws, size_t ws_size,
                              hipStream_t stream) {
    const float* points = (const float*)d_in[0];   // (N,4) f32
    const float* boxes  = (const float*)d_in[1];   // (B,M,7) f32
    int* out_idx = (int*)d_out;                    // (B,M,512)
    int* out_num = (int*)d_out + NBOX * NFPS;      // (B,M)

    unsigned* bits = (unsigned*)d_ws;
    float*    prep = (float*)((char*)d_ws + PREP_OFF);
    int*      done = (int*)((char*)d_ws + DONE_OFF);

    roi_prep<<<1, NBOX, 0, stream>>>(boxes, prep, done);
    roi_fused<<<dim3(NSEG, NGRP), THREADS, 0, stream>>>(points, prep, bits, done,
                                                        out_idx, out_num);
}

// Round 4
// 24.600 us; speedup vs baseline: 3.1167x; 3.1167x over previous
//
#include <hip/hip_runtime.h>
#include <math.h>

#define NPTS   131072
#define BATCH  2
#define MBOX   128
#define NBOX   (BATCH * MBOX)       // 256
#define NFPS   512
#define THREADS 256

#define NSEG   64
#define SEGPTS 2048                 // points per phase-1 block
#define GRPBOX 16                   // boxes per phase-1 block
#define NGRP   (NBOX / GRPBOX)      // 16
#define DWPB   (NPTS / 32)          // 4096 bitmask dwords per box

// ---------------- Phase 1: build per-box inside-bitmask -----------------
__global__ __launch_bounds__(THREADS)
void roi_phase1(const float* __restrict__ points,   // (N,4): [b, x, y, z]
                const float* __restrict__ boxes,    // (B,M,7)
                unsigned* __restrict__ bits)        // (NBOX, DWPB)
{
    const int seg  = blockIdx.x;
    const int grp  = blockIdx.y;
    const int tid  = threadIdx.x;
    const int lane = tid & 63;
    const int w    = tid >> 6;

    // 1) issue this wave's 8 point loads FIRST (latency overlaps the trig)
    const float4* p4 = (const float4*)points;
    const int wbase = seg * SEGPTS + w * 512;
    float4 praw[8];
    #pragma unroll
    for (int j = 0; j < 8; ++j) praw[j] = p4[wbase + j * 64 + lane];

    // 2) box params while loads are in flight.
    //    fp32 ops verbatim from the passing kernels (bit-identical decisions).
    __shared__ float s_box[GRPBOX][8];
    if (tid < GRPBOX) {
        const int box = grp * GRPBOX + tid;
        const float* bx = boxes + box * 7;
        const float bdx = bx[3], bdy = bx[4], bdz = bx[5], h = bx[6];
        s_box[tid][0] = bx[0];
        s_box[tid][1] = bx[1];
        s_box[tid][2] = bx[2];
        s_box[tid][3] = __fmul_rn(__fadd_rn(bdy, 2.0f), 0.5f);
        s_box[tid][4] = __fmul_rn(__fadd_rn(bdx, 2.0f), 0.5f);
        s_box[tid][5] = __fmul_rn(__fadd_rn(bdz, 2.0f), 0.5f);
        const float hp = -__fadd_rn(h, 1.5707963705062866f);  // fl32(pi/2)
        s_box[tid][6] = (float)cos((double)hp);
        s_box[tid][7] = (float)sin((double)hp);
    }
    __syncthreads();

    // 3) unpack + per-point batch masks (box-independent, hoisted)
    const int bB = grp >> 3;               // batch of this group's boxes (uniform)
    float px[8], py[8], pz[8];
    unsigned long long bok[8];
    #pragma unroll
    for (int j = 0; j < 8; ++j) {
        px[j] = praw[j].y; py[j] = praw[j].z; pz[j] = praw[j].w;
        bok[j] = __ballot((int)praw[j].x == bB);
    }

    // 4) 16 boxes: ballots ARE the output dwords
    unsigned* wdst = bits + (size_t)grp * GRPBOX * DWPB + seg * 64 + w * 16;
    #pragma unroll 2
    for (int bi = 0; bi < GRPBOX; ++bi) {
        const float cx = s_box[bi][0], cy = s_box[bi][1], cz = s_box[bi][2];
        const float hx = s_box[bi][3], hy = s_box[bi][4], hz = s_box[bi][5];
        const float c  = s_box[bi][6], s  = s_box[bi][7];
        unsigned long long bal[8];
        #pragma unroll
        for (int j = 0; j < 8; ++j) {
            const float ddx = __fsub_rn(px[j], cx);
            const float ddy = __fsub_rn(py[j], cy);
            const float ddz = __fsub_rn(pz[j], cz);
            const float lx  = __fadd_rn(__fmul_rn(ddx, c), __fmul_rn(ddy, s));
            const float ly  = __fadd_rn(__fmul_rn(-ddx, s), __fmul_rn(ddy, c));
            bal[j] = __ballot((fabsf(lx) <= hx) & (fabsf(ly) <= hy) &
                              (fabsf(ddz) <= hz)) & bok[j];
        }
        if (lane == 0) {
            uint4* dst = (uint4*)(wdst + bi * DWPB);
            dst[0] = make_uint4((unsigned)bal[0], (unsigned)(bal[0] >> 32),
                                (unsigned)bal[1], (unsigned)(bal[1] >> 32));
            dst[1] = make_uint4((unsigned)bal[2], (unsigned)(bal[2] >> 32),
                                (unsigned)bal[3], (unsigned)(bal[3] >> 32));
            dst[2] = make_uint4((unsigned)bal[4], (unsigned)(bal[4] >> 32),
                                (unsigned)bal[5], (unsigned)(bal[5] >> 32));
            dst[3] = make_uint4((unsigned)bal[6], (unsigned)(bal[6] >> 32),
                                (unsigned)bal[7], (unsigned)(bal[7] >> 32));
        }
    }
}

// ------------- Phase 2: ordered compaction of the bitmask ---------------
// 1024 threads: thread t owns one uint4 = points [t*128, (t+1)*128).
__global__ __launch_bounds__(1024)
void roi_phase2(const unsigned* __restrict__ bits,  // (NBOX, DWPB)
                int* __restrict__ out_idx,          // (NBOX, 512)
                int* __restrict__ out_num)          // (NBOX)
{
    const int box  = blockIdx.x;
    const int tid  = threadIdx.x;
    const int lane = tid & 63;
    const int w    = tid >> 6;

    __shared__ int s_wsum[1024 / 64];

    const uint4 q = ((const uint4*)(bits + (size_t)box * DWPB))[tid];  // coalesced
    const int cnt = __popc(q.x) + __popc(q.y) + __popc(q.z) + __popc(q.w);

    // wave inclusive scan
    int incl = cnt;
    #pragma unroll
    for (int off = 1; off < 64; off <<= 1) {
        const int x = __shfl_up(incl, off, 64);
        if (lane >= off) incl += x;
    }
    if (lane == 63) s_wsum[w] = incl;
    __syncthreads();

    int wpre = 0, total = 0;
    #pragma unroll
    for (int ww = 0; ww < 1024 / 64; ++ww) {
        const int x = s_wsum[ww];
        if (ww < w) wpre += x;
        total += x;
    }
    int pos = wpre + (incl - cnt);
    const int pn = total < NFPS ? total : NFPS;

    const int obase = box * NFPS;
    if (tid < NFPS && tid >= pn) out_idx[obase + tid] = 0;   // zero tail

    unsigned v[4] = {q.x, q.y, q.z, q.w};
    const int pt0 = tid * 128;
    #pragma unroll
    for (int i = 0; i < 4; ++i) {
        unsigned x = v[i];
        while (x) {
            const int b = __ffs(x) - 1;
            if (pos < NFPS) out_idx[obase + pos] = pt0 + i * 32 + b;
            ++pos;
            x &= x - 1;
        }
    }
    if (tid == 0) out_num[box] = pn;
}

extern "C" void kernel_launch(void* const* d_in, const int* in_sizes, int n_in,
                              void* d_out, int out_size, void* d_ws, size_t ws_size,
                              hipStream_t stream) {
    const float* points = (const float*)d_in[0];   // (N,4) f32
    const float* boxes  = (const float*)d_in[1];   // (B,M,7) f32
    int* out_idx = (int*)d_out;                    // (B,M,512)
    int* out_num = (int*)d_out + NBOX * NFPS;      // (B,M)
    unsigned* bits = (unsigned*)d_ws;              // NBOX * DWPB dwords = 4 MiB

    roi_phase1<<<dim3(NSEG, NGRP), THREADS, 0, stream>>>(points, boxes, bits);
    roi_phase2<<<NBOX, 1024, 0, stream>>>(bits, out_idx, out_num);
}